// Round 20
// baseline (486.277 us; speedup 1.0000x reference)
//
#include <hip/hip_runtime.h>

#define EXPERTS 8
#define HID 2048
#define INTER 4096
#define BTOK 2048
#define NASSIGN 4096   // BTOK * TOPK
#define NTSLOTS 24     // BM=256: max sum_e ceil(cnt_e/256) = 16+8

typedef float f32x4 __attribute__((ext_vector_type(4)));
typedef __bf16 bf16x8 __attribute__((ext_vector_type(8)));
typedef unsigned short ushortx8 __attribute__((ext_vector_type(8)));

__device__ __forceinline__ unsigned short f2bf(float f) {
  union { float f; unsigned int u; } v; v.f = f;
  unsigned int r = v.u + 0x7fffu + ((v.u >> 16) & 1u);   // RNE
  return (unsigned short)(r >> 16);
}

// ---------------- workspace layout (bytes) ----------------
#define XB_OFF   0ULL                                   // [BTOK][HID] bf16 = 8 MiB
#define GB_OFF   (XB_OFF + 8388608ULL)                  // [NASSIGN][INTER] bf16 = 32 MiB
#define Y_OFF    (GB_OFF + 33554432ULL)                 // [NASSIGN][HID] f32 = 32 MiB
#define ROWS_OFF (Y_OFF  + 33554432ULL)                 // 4096 int
#define OFFS_OFF (ROWS_OFF + 16384ULL)                  // 9 int (padded 64B)
#define TILE_OFF (OFFS_OFF + 64ULL)                     // 24 int

// ---------------- prep: routing (block 0) + x f32->bf16 ----------------
__global__ void prep_kernel(const int* __restrict__ eraw,
                            const float* __restrict__ x,
                            unsigned short* __restrict__ xb,
                            int* __restrict__ rows, int* __restrict__ offs_g,
                            int* __restrict__ tiles)
{
  const int b = blockIdx.x;
  const int tid = threadIdx.x;

  if (b == 0) {
    __shared__ int cnt[256 * 8];
    __shared__ int offs_s[9];
    __shared__ int tot[8];
    __shared__ int found_odd;
    if (tid == 0) found_odd = 0;
    __syncthreads();
    int any = 0;
    for (int j = 0; j < 8; ++j) {
      int a = tid * 8 + j;
      any |= (eraw[2 * a + 1] != 0);
    }
    if (any) atomicOr(&found_odd, 1);
    __syncthreads();
    const bool i64 = (found_odd == 0);
    int lc[8];
    for (int e = 0; e < 8; ++e) lc[e] = 0;
    for (int j = 0; j < 16; ++j) {
      int a = tid * 16 + j;
      int e = i64 ? eraw[2 * a] : eraw[a];
      lc[e]++;
    }
    for (int e = 0; e < 8; ++e) cnt[tid * 8 + e] = lc[e];
    __syncthreads();
    if (tid < 8) {
      int run = 0;
      for (int t = 0; t < 256; ++t) {
        int v = cnt[t * 8 + tid];
        cnt[t * 8 + tid] = run;
        run += v;
      }
      tot[tid] = run;
    }
    __syncthreads();
    if (tid == 0) {
      int o = 0;
      for (int e = 0; e < 8; ++e) { offs_s[e] = o; o += tot[e]; }
      offs_s[8] = o;
      int s = 0;
      for (int e = 0; e < 8; ++e) {
        int nmt = (tot[e] + 255) >> 8;        // BM=256
        for (int m = 0; m < nmt; ++m) tiles[s++] = (e << 16) | m;
      }
      for (; s < NTSLOTS; ++s) tiles[s] = -1;
    }
    __syncthreads();
    if (tid < 9) offs_g[tid] = offs_s[tid];
    int lc2[8];
    for (int e = 0; e < 8; ++e) lc2[e] = 0;
    for (int j = 0; j < 16; ++j) {
      int a = tid * 16 + j;
      int e = i64 ? eraw[2 * a] : eraw[a];
      rows[offs_s[e] + cnt[tid * 8 + e] + lc2[e]] = a;
      lc2[e]++;
    }
  } else {
    long idx = (long)(b - 1) * 256 + tid;
    float4 v = *(const float4*)&x[idx * 4];
    unsigned int lo = (unsigned int)f2bf(v.x) | ((unsigned int)f2bf(v.y) << 16);
    unsigned int hi = (unsigned int)f2bf(v.z) | ((unsigned int)f2bf(v.w) << 16);
    uint2 p; p.x = lo; p.y = hi;
    *(uint2*)&xb[idx * 4] = p;
  }
}

// ---------------- gate+up grouped GEMM: 64x64 wave tiles --------------------
// BM=256, BN=64, 256 threads = 4 waves, each wave computes 64 rows x 64 cols
// of BOTH matmuls (af[4] shared; b1f[4]/b3f[4] reused across 4 row strips).
// LDS bytes/FLOP drops 0.0305 -> 0.0229 vs R19 (the binding pipe).
// Same single-barrier schedule: convert(t) -> LOAD_B(t+1) -> sync ->
// STAGE_A(t+1) -> MFMA(t). LDS 48 KiB; launch_bounds(256,2) for ~210 VGPR.
__global__ __launch_bounds__(256, 2) void gemm_gateup(
    const unsigned short* __restrict__ xb,
    const float* __restrict__ w1,
    const float* __restrict__ w3,
    unsigned short* __restrict__ gb,
    const int* __restrict__ rows,
    const int* __restrict__ offs,
    const int* __restrict__ tiles)
{
  const int te = tiles[blockIdx.y];
  if (te < 0) return;
  const int e  = te >> 16, mt = te & 0xffff;
  const int off = offs[e];
  const int cnt = offs[e + 1] - off;
  const int nt  = blockIdx.x;                 // 64 N-tiles of 64 over INTER

  __shared__ __align__(16) unsigned short As[2][256 * 32];    // 32 KiB
  __shared__ __align__(16) unsigned short B1bf[2][4 * 64 * 8];//  8 KiB
  __shared__ __align__(16) unsigned short B3bf[2][4 * 64 * 8];//  8 KiB

  const int tid  = threadIdx.x;
  const int lane = tid & 63;
  const int wr   = tid >> 6;                  // 4 waves = 4 row strips

  // A staging: 1024 slots (256 rows x 4 segs) over 256 threads x 4 chunks
  const unsigned short* aptr[4];
  #pragma unroll
  for (int c = 0; c < 4; ++c) {
    int idx = tid + c * 256;
    int row = idx >> 2, seg = idx & 3;
    int rr = off + mt * 256 + row;
    int rv = (rr < off + cnt) ? rr : (off + cnt - 1);
    long tok = rows[rv] >> 1;
    aptr[c] = xb + tok * HID + seg * 8;
  }
  // B reg-staging: thread -> (n = tid&63, k-oct = tid>>6); stages B1 AND B3
  const int bn = tid & 63, bk8 = tid >> 6;
  const float* b1base = w1 + ((long)e * HID + bk8 * 8) * INTER + nt * 64 + bn;
  const float* b3base = w3 + ((long)e * HID + bk8 * 8) * INTER + nt * 64 + bn;

  auto STAGE_A = [&](int abuf, long k32) {
    #pragma unroll
    for (int c = 0; c < 4; ++c)
      __builtin_amdgcn_global_load_lds(
          (const __attribute__((address_space(1))) unsigned int*)(aptr[c] + k32),
          (__attribute__((address_space(3))) unsigned int*)(&As[abuf][(tid + c * 256) * 8]),
          16, 0, 0);
  };

  float rB1[8], rB3[8];
  auto LOAD_B = [&](int t) {
    const float* p1 = b1base + (long)t * 32 * INTER;
    const float* p3 = b3base + (long)t * 32 * INTER;
    #pragma unroll
    for (int j = 0; j < 8; ++j) {
      rB1[j] = p1[(long)j * INTER];
      rB3[j] = p3[(long)j * INTER];
    }
  };

  f32x4 acc1[4][4], acc3[4][4];
  #pragma unroll
  for (int i = 0; i < 4; ++i)
    #pragma unroll
    for (int j = 0; j < 4; ++j) { acc1[i][j] = (f32x4)0.0f; acc3[i][j] = (f32x4)0.0f; }

  LOAD_B(0);
  STAGE_A(0, 0);

  const int NIT = HID / 32;   // 64
  for (int t = 0; t < NIT; ++t) {
    const int p = t & 1;
    // convert B(t) from regs -> Bbf[p] (one b128 write per matrix)
    {
      bf16x8 p1, p3;
      #pragma unroll
      for (int j = 0; j < 8; ++j) {
        p1[j] = (__bf16)rB1[j];
        p3[j] = (__bf16)rB3[j];
      }
      *(bf16x8*)&B1bf[p][(bk8 * 64 + bn) * 8] = p1;
      *(bf16x8*)&B3bf[p][(bk8 * 64 + bn) * 8] = p3;
    }
    if (t + 1 < NIT) LOAD_B(t + 1);          // spans the barrier (VGPR loads)
    __syncthreads();                         // publish Bbf(t); drain As(t)
    if (t + 1 < NIT) STAGE_A((t + 1) & 1, (long)(t + 1) * 32);
    const int k8 = lane >> 4;
    bf16x8 af[4], b1f[4], b3f[4];
    #pragma unroll
    for (int f = 0; f < 4; ++f)
      af[f] = __builtin_bit_cast(bf16x8, *(const ushortx8*)&As[p][(wr * 64 + f * 16 + (lane & 15)) * 32 + k8 * 8]);
    #pragma unroll
    for (int j = 0; j < 4; ++j) {
      b1f[j] = __builtin_bit_cast(bf16x8, *(const ushortx8*)&B1bf[p][(k8 * 64 + j * 16 + (lane & 15)) * 8]);
      b3f[j] = __builtin_bit_cast(bf16x8, *(const ushortx8*)&B3bf[p][(k8 * 64 + j * 16 + (lane & 15)) * 8]);
    }
    #pragma unroll
    for (int i = 0; i < 4; ++i)
      #pragma unroll
      for (int j = 0; j < 4; ++j) {
        acc1[i][j] = __builtin_amdgcn_mfma_f32_16x16x32_bf16(af[i], b1f[j], acc1[i][j], 0, 0, 0);
        acc3[i][j] = __builtin_amdgcn_mfma_f32_16x16x32_bf16(af[i], b3f[j], acc3[i][j], 0, 0, 0);
      }
  }

  const int rtop = off + cnt;
  const int grb  = off + mt * 256 + wr * 64;
  const int gcb  = nt * 64;
  #pragma unroll
  for (int i = 0; i < 4; ++i) {
    #pragma unroll
    for (int j = 0; j < 4; ++j) {
      int gc = gcb + j * 16 + (lane & 15);
      #pragma unroll
      for (int qq = 0; qq < 4; ++qq) {
        int gr = grb + i * 16 + (lane >> 4) * 4 + qq;
        if (gr < rtop) {
          float g = acc1[i][j][qq];
          float u = acc3[i][j][qq];
          float s = g / (1.0f + __expf(-g));
          gb[(long)gr * INTER + gc] = f2bf(s * u);
        }
      }
    }
  }
}

// ---------------- down grouped GEMM: 64x64 wave tiles -----------------------
// BM=256, BN=64, 256 threads = 4 waves. acc[4][4] (~130 VGPR -> bounds(256,3)).
// LDS 40 KiB.
__global__ __launch_bounds__(256, 3) void gemm_down(
    const unsigned short* __restrict__ gbin,
    const float* __restrict__ w2,
    float* __restrict__ y,
    const int* __restrict__ rows,
    const int* __restrict__ offs,
    const int* __restrict__ tiles)
{
  const int te = tiles[blockIdx.y];
  if (te < 0) return;
  const int e  = te >> 16, mt = te & 0xffff;
  const int off = offs[e];
  const int cnt = offs[e + 1] - off;
  const int nt  = blockIdx.x;                 // 32 N-tiles of 64 over HID

  __shared__ __align__(16) unsigned short As[2][256 * 32];    // 32 KiB
  __shared__ __align__(16) unsigned short Bbf[2][4 * 64 * 8]; //  8 KiB

  const int tid  = threadIdx.x;
  const int lane = tid & 63;
  const int wr   = tid >> 6;

  const unsigned short* aptr[4];
  #pragma unroll
  for (int c = 0; c < 4; ++c) {
    int idx = tid + c * 256;
    int row = idx >> 2, seg = idx & 3;
    int rr = off + mt * 256 + row;
    int rv = (rr < off + cnt) ? rr : (off + cnt - 1);
    aptr[c] = gbin + (long)rv * INTER + seg * 8;
  }
  const int bn = tid & 63, bk8 = tid >> 6;
  const float* bbase = w2 + ((long)e * INTER + bk8 * 8) * HID + nt * 64 + bn;

  auto STAGE_A = [&](int abuf, long k32) {
    #pragma unroll
    for (int c = 0; c < 4; ++c)
      __builtin_amdgcn_global_load_lds(
          (const __attribute__((address_space(1))) unsigned int*)(aptr[c] + k32),
          (__attribute__((address_space(3))) unsigned int*)(&As[abuf][(tid + c * 256) * 8]),
          16, 0, 0);
  };

  float rB[8];
  auto LOAD_B = [&](int t) {
    const float* p = bbase + (long)t * 32 * HID;
    #pragma unroll
    for (int j = 0; j < 8; ++j) rB[j] = p[(long)j * HID];
  };

  f32x4 acc[4][4];
  #pragma unroll
  for (int i = 0; i < 4; ++i)
    #pragma unroll
    for (int j = 0; j < 4; ++j) acc[i][j] = (f32x4)0.0f;

  LOAD_B(0);
  STAGE_A(0, 0);

  const int NIT = INTER / 32;   // 128
  for (int t = 0; t < NIT; ++t) {
    const int p = t & 1;
    {
      bf16x8 pk;
      #pragma unroll
      for (int j = 0; j < 8; ++j) pk[j] = (__bf16)rB[j];
      *(bf16x8*)&Bbf[p][(bk8 * 64 + bn) * 8] = pk;
    }
    if (t + 1 < NIT) LOAD_B(t + 1);
    __syncthreads();
    if (t + 1 < NIT) STAGE_A((t + 1) & 1, (long)(t + 1) * 32);
    const int k8 = lane >> 4;
    bf16x8 af[4], bf[4];
    #pragma unroll
    for (int f = 0; f < 4; ++f)
      af[f] = __builtin_bit_cast(bf16x8, *(const ushortx8*)&As[p][(wr * 64 + f * 16 + (lane & 15)) * 32 + k8 * 8]);
    #pragma unroll
    for (int j = 0; j < 4; ++j)
      bf[j] = __builtin_bit_cast(bf16x8, *(const ushortx8*)&Bbf[p][(k8 * 64 + j * 16 + (lane & 15)) * 8]);
    #pragma unroll
    for (int i = 0; i < 4; ++i)
      #pragma unroll
      for (int j = 0; j < 4; ++j)
        acc[i][j] = __builtin_amdgcn_mfma_f32_16x16x32_bf16(af[i], bf[j], acc[i][j], 0, 0, 0);
  }

  const int rtop = off + cnt;
  const int grb  = off + mt * 256 + wr * 64;
  const int gcb  = nt * 64;
  #pragma unroll
  for (int i = 0; i < 4; ++i) {
    #pragma unroll
    for (int j = 0; j < 4; ++j) {
      int gc = gcb + j * 16 + (lane & 15);
      #pragma unroll
      for (int q = 0; q < 4; ++q) {
        int gr = grb + i * 16 + (lane >> 4) * 4 + q;
        if (gr < rtop) {
          int a = rows[gr];
          y[(long)a * HID + gc] = acc[i][j][q];
        }
      }
    }
  }
}

// ---------------- combine: out[t] = ew0*Y[2t] + ew1*Y[2t+1] ----------------
__global__ void combine_kernel(const float* __restrict__ Y,
                               const float* __restrict__ ew,
                               float* __restrict__ out)
{
  int idx = blockIdx.x * 256 + threadIdx.x;
  int t = idx >> 9;
  int h = (idx & 511) * 4;
  float w0 = ew[2 * t], w1 = ew[2 * t + 1];
  float4 y0 = *(const float4*)&Y[(long)(2 * t) * HID + h];
  float4 y1 = *(const float4*)&Y[(long)(2 * t + 1) * HID + h];
  float4 o;
  o.x = w0 * y0.x + w1 * y1.x;
  o.y = w0 * y0.y + w1 * y1.y;
  o.z = w0 * y0.z + w1 * y1.z;
  o.w = w0 * y0.w + w1 * y1.w;
  *(float4*)&out[(long)t * HID + h] = o;
}

extern "C" void kernel_launch(void* const* d_in, const int* in_sizes, int n_in,
                              void* d_out, int out_size, void* d_ws, size_t ws_size,
                              hipStream_t stream) {
  const float* x   = (const float*)d_in[0];
  const int*   eix = (const int*)d_in[1];
  const float* ew  = (const float*)d_in[2];
  const float* w1  = (const float*)d_in[3];
  const float* w2  = (const float*)d_in[4];
  const float* w3  = (const float*)d_in[5];
  float* out = (float*)d_out;

  char* ws = (char*)d_ws;
  unsigned short* xb  = (unsigned short*)(ws + XB_OFF);
  unsigned short* gb  = (unsigned short*)(ws + GB_OFF);
  float*          y   = (float*)(ws + Y_OFF);
  int*            rows  = (int*)(ws + ROWS_OFF);
  int*            offs  = (int*)(ws + OFFS_OFF);
  int*            tiles = (int*)(ws + TILE_OFF);

  prep_kernel<<<4097, 256, 0, stream>>>(eix, x, xb, rows, offs, tiles);
  gemm_gateup<<<dim3(INTER / 64, NTSLOTS), 256, 0, stream>>>(
      xb, w1, w3, gb, rows, offs, tiles);
  gemm_down<<<dim3(HID / 64, NTSLOTS), 256, 0, stream>>>(
      gb, w2, y, rows, offs, tiles);
  combine_kernel<<<4096, 256, 0, stream>>>(y, ew, out);
}

// Round 21
// 433.040 us; speedup vs baseline: 1.1229x; 1.1229x over previous
//
#include <hip/hip_runtime.h>

#define EXPERTS 8
#define HID 2048
#define INTER 4096
#define BTOK 2048
#define NASSIGN 4096   // BTOK * TOPK
#define NTSLOTS 24     // BM=256: max sum_e ceil(cnt_e/256) = 16+8

typedef float f32x4 __attribute__((ext_vector_type(4)));
typedef __bf16 bf16x8 __attribute__((ext_vector_type(8)));
typedef unsigned short ushortx8 __attribute__((ext_vector_type(8)));

__device__ __forceinline__ unsigned short f2bf(float f) {
  union { float f; unsigned int u; } v; v.f = f;
  unsigned int r = v.u + 0x7fffu + ((v.u >> 16) & 1u);   // RNE
  return (unsigned short)(r >> 16);
}

// ---------------- workspace layout (bytes) ----------------
#define XB_OFF   0ULL                                   // [BTOK][HID] bf16 = 8 MiB
#define GB_OFF   (XB_OFF + 8388608ULL)                  // [NASSIGN][INTER] bf16 = 32 MiB
#define Y_OFF    (GB_OFF + 33554432ULL)                 // [NASSIGN][HID] f32 = 32 MiB
#define ROWS_OFF (Y_OFF  + 33554432ULL)                 // 4096 int
#define OFFS_OFF (ROWS_OFF + 16384ULL)                  // 9 int (padded 64B)
#define TILE_OFF (OFFS_OFF + 64ULL)                     // 24 int

// ---------------- prep: routing (block 0) + x f32->bf16 ----------------
__global__ void prep_kernel(const int* __restrict__ eraw,
                            const float* __restrict__ x,
                            unsigned short* __restrict__ xb,
                            int* __restrict__ rows, int* __restrict__ offs_g,
                            int* __restrict__ tiles)
{
  const int b = blockIdx.x;
  const int tid = threadIdx.x;

  if (b == 0) {
    __shared__ int cnt[256 * 8];
    __shared__ int offs_s[9];
    __shared__ int tot[8];
    __shared__ int found_odd;
    if (tid == 0) found_odd = 0;
    __syncthreads();
    int any = 0;
    for (int j = 0; j < 8; ++j) {
      int a = tid * 8 + j;
      any |= (eraw[2 * a + 1] != 0);
    }
    if (any) atomicOr(&found_odd, 1);
    __syncthreads();
    const bool i64 = (found_odd == 0);
    int lc[8];
    for (int e = 0; e < 8; ++e) lc[e] = 0;
    for (int j = 0; j < 16; ++j) {
      int a = tid * 16 + j;
      int e = i64 ? eraw[2 * a] : eraw[a];
      lc[e]++;
    }
    for (int e = 0; e < 8; ++e) cnt[tid * 8 + e] = lc[e];
    __syncthreads();
    if (tid < 8) {
      int run = 0;
      for (int t = 0; t < 256; ++t) {
        int v = cnt[t * 8 + tid];
        cnt[t * 8 + tid] = run;
        run += v;
      }
      tot[tid] = run;
    }
    __syncthreads();
    if (tid == 0) {
      int o = 0;
      for (int e = 0; e < 8; ++e) { offs_s[e] = o; o += tot[e]; }
      offs_s[8] = o;
      int s = 0;
      for (int e = 0; e < 8; ++e) {
        int nmt = (tot[e] + 255) >> 8;        // BM=256
        for (int m = 0; m < nmt; ++m) tiles[s++] = (e << 16) | m;
      }
      for (; s < NTSLOTS; ++s) tiles[s] = -1;
    }
    __syncthreads();
    if (tid < 9) offs_g[tid] = offs_s[tid];
    int lc2[8];
    for (int e = 0; e < 8; ++e) lc2[e] = 0;
    for (int j = 0; j < 16; ++j) {
      int a = tid * 16 + j;
      int e = i64 ? eraw[2 * a] : eraw[a];
      rows[offs_s[e] + cnt[tid * 8 + e] + lc2[e]] = a;
      lc2[e]++;
    }
  } else {
    long idx = (long)(b - 1) * 256 + tid;
    float4 v = *(const float4*)&x[idx * 4];
    unsigned int lo = (unsigned int)f2bf(v.x) | ((unsigned int)f2bf(v.y) << 16);
    unsigned int hi = (unsigned int)f2bf(v.z) | ((unsigned int)f2bf(v.w) << 16);
    uint2 p; p.x = lo; p.y = hi;
    *(uint2*)&xb[idx * 4] = p;
  }
}

// ---------------- gate+up grouped GEMM: BM=256, 512 threads, 8 waves --------
// R19-proven structure + T4 counted-wait barrier: the old __syncthreads
// drained vmcnt(0) including LOAD_B(t+1)'s just-issued 8 VGPR loads (~300-
// 500cy exposed/iter). Now: s_waitcnt vmcnt(8) lgkmcnt(0) completes ONLY
// STAGE_A(t)'s 2 gload_lds (As must be valid post-barrier) + convert's Bbf
// ds_writes (cross-wave, R16 lesson); LOAD_B(t+1) stays in flight with a
// full iteration of cover.
__global__ __launch_bounds__(512, 4) void gemm_gateup(
    const unsigned short* __restrict__ xb,
    const float* __restrict__ w1,
    const float* __restrict__ w3,
    unsigned short* __restrict__ gb,
    const int* __restrict__ rows,
    const int* __restrict__ offs,
    const int* __restrict__ tiles)
{
  const int te = tiles[blockIdx.y];
  if (te < 0) return;
  const int e  = te >> 16, mt = te & 0xffff;
  const int off = offs[e];
  const int cnt = offs[e + 1] - off;
  const int nt  = blockIdx.x;                 // 64 N-tiles of 64 over INTER

  __shared__ __align__(16) unsigned short As[2][256 * 32];    // 32 KiB
  __shared__ __align__(16) unsigned short B1bf[2][4 * 64 * 8];//  8 KiB
  __shared__ __align__(16) unsigned short B3bf[2][4 * 64 * 8];//  8 KiB

  const int tid  = threadIdx.x;
  const int lane = tid & 63;
  const int wave = tid >> 6;                  // 8 waves
  const int wr = wave >> 1, wc = wave & 1;    // wr: 4x64 rows, wc: 2x32 cols

  // A staging: 1024 slots (256 rows x 4 segs) over 512 threads x 2 chunks
  const unsigned short* aptr[2];
  #pragma unroll
  for (int c = 0; c < 2; ++c) {
    int idx = tid + c * 512;
    int row = idx >> 2, seg = idx & 3;
    int rr = off + mt * 256 + row;
    int rv = (rr < off + cnt) ? rr : (off + cnt - 1);
    long tok = rows[rv] >> 1;
    aptr[c] = xb + tok * HID + seg * 8;
  }
  // B reg-staging: tid<256 -> B1, tid>=256 -> B3; slot = tid&255
  const int bslot = tid & 255;
  const int bn = bslot & 63, bk8 = bslot >> 6;   // bk8 in 0..3
  const bool isB1 = (tid < 256);
  const float* wsel = isB1 ? w1 : w3;
  const float* bbase = wsel + ((long)e * HID + bk8 * 8) * INTER + nt * 64 + bn;

  auto STAGE_A = [&](int abuf, long k32) {
    #pragma unroll
    for (int c = 0; c < 2; ++c)
      __builtin_amdgcn_global_load_lds(
          (const __attribute__((address_space(1))) unsigned int*)(aptr[c] + k32),
          (__attribute__((address_space(3))) unsigned int*)(&As[abuf][(tid + c * 512) * 8]),
          16, 0, 0);
  };

  float rB[8];
  auto LOAD_B = [&](int t) {
    const float* p = bbase + (long)t * 32 * INTER;
    #pragma unroll
    for (int j = 0; j < 8; ++j) rB[j] = p[(long)j * INTER];
  };

  f32x4 acc1[4][2], acc3[4][2];
  #pragma unroll
  for (int i = 0; i < 4; ++i)
    #pragma unroll
    for (int j = 0; j < 2; ++j) { acc1[i][j] = (f32x4)0.0f; acc3[i][j] = (f32x4)0.0f; }

  LOAD_B(0);
  STAGE_A(0, 0);

  const int NIT = HID / 32;   // 64
  for (int t = 0; t < NIT; ++t) {
    const int p = t & 1;
    // convert B(t) from regs -> Bbf[p] (one b128 write, banks bn*4: min alias)
    {
      bf16x8 pk;
      #pragma unroll
      for (int j = 0; j < 8; ++j) pk[j] = (__bf16)rB[j];
      if (isB1) *(bf16x8*)&B1bf[p][(bk8 * 64 + bn) * 8] = pk;
      else      *(bf16x8*)&B3bf[p][(bk8 * 64 + bn) * 8] = pk;
    }
    if (t + 1 < NIT) LOAD_B(t + 1);          // spans the barrier (VGPR loads)
    // T4 counted wait: queue = [STAGE_A(t):2, LOAD_B(t+1):8]
    if (t + 1 < NIT) { asm volatile("s_waitcnt vmcnt(8) lgkmcnt(0)" ::: "memory"); }
    else             { asm volatile("s_waitcnt vmcnt(0) lgkmcnt(0)" ::: "memory"); }
    __builtin_amdgcn_s_barrier();
    asm volatile("" ::: "memory");
    if (t + 1 < NIT) STAGE_A((t + 1) & 1, (long)(t + 1) * 32);
    const int k8 = lane >> 4;
    bf16x8 af[4], b1f[2], b3f[2];
    #pragma unroll
    for (int f = 0; f < 4; ++f)
      af[f] = __builtin_bit_cast(bf16x8, *(const ushortx8*)&As[p][(wr * 64 + f * 16 + (lane & 15)) * 32 + k8 * 8]);
    #pragma unroll
    for (int j = 0; j < 2; ++j) {
      b1f[j] = __builtin_bit_cast(bf16x8, *(const ushortx8*)&B1bf[p][(k8 * 64 + wc * 32 + j * 16 + (lane & 15)) * 8]);
      b3f[j] = __builtin_bit_cast(bf16x8, *(const ushortx8*)&B3bf[p][(k8 * 64 + wc * 32 + j * 16 + (lane & 15)) * 8]);
    }
    #pragma unroll
    for (int i = 0; i < 4; ++i)
      #pragma unroll
      for (int j = 0; j < 2; ++j) {
        acc1[i][j] = __builtin_amdgcn_mfma_f32_16x16x32_bf16(af[i], b1f[j], acc1[i][j], 0, 0, 0);
        acc3[i][j] = __builtin_amdgcn_mfma_f32_16x16x32_bf16(af[i], b3f[j], acc3[i][j], 0, 0, 0);
      }
  }

  const int rtop = off + cnt;
  const int grb  = off + mt * 256 + wr * 64;
  const int gcb  = nt * 64 + wc * 32;
  #pragma unroll
  for (int i = 0; i < 4; ++i) {
    #pragma unroll
    for (int j = 0; j < 2; ++j) {
      int gc = gcb + j * 16 + (lane & 15);
      #pragma unroll
      for (int qq = 0; qq < 4; ++qq) {
        int gr = grb + i * 16 + (lane >> 4) * 4 + qq;
        if (gr < rtop) {
          float g = acc1[i][j][qq];
          float u = acc3[i][j][qq];
          float s = g / (1.0f + __expf(-g));
          gb[(long)gr * INTER + gc] = f2bf(s * u);
        }
      }
    }
  }
}

// ---------------- down grouped GEMM: BM=256, 512 threads, 8 waves -----------
// Same T4 counted-wait. Non-staging waves (tid>=256, wave-uniform) have
// queue [STAGE_A:2] only -> they wait vmcnt(0) (their loads are old; cheap).
__global__ __launch_bounds__(512, 4) void gemm_down(
    const unsigned short* __restrict__ gbin,
    const float* __restrict__ w2,
    float* __restrict__ y,
    const int* __restrict__ rows,
    const int* __restrict__ offs,
    const int* __restrict__ tiles)
{
  const int te = tiles[blockIdx.y];
  if (te < 0) return;
  const int e  = te >> 16, mt = te & 0xffff;
  const int off = offs[e];
  const int cnt = offs[e + 1] - off;
  const int nt  = blockIdx.x;                 // 32 N-tiles of 64 over HID

  __shared__ __align__(16) unsigned short As[2][256 * 32];    // 32 KiB
  __shared__ __align__(16) unsigned short Bbf[2][4 * 64 * 8]; //  8 KiB

  const int tid  = threadIdx.x;
  const int lane = tid & 63;
  const int wave = tid >> 6;
  const int wr = wave >> 1, wc = wave & 1;

  const unsigned short* aptr[2];
  #pragma unroll
  for (int c = 0; c < 2; ++c) {
    int idx = tid + c * 512;
    int row = idx >> 2, seg = idx & 3;
    int rr = off + mt * 256 + row;
    int rv = (rr < off + cnt) ? rr : (off + cnt - 1);
    aptr[c] = gbin + (long)rv * INTER + seg * 8;
  }
  const int bslot = tid & 255;
  const int bn = bslot & 63, bk8 = bslot >> 6;
  const bool doB = (tid < 256);
  const float* bbase = w2 + ((long)e * INTER + bk8 * 8) * HID + nt * 64 + bn;

  auto STAGE_A = [&](int abuf, long k32) {
    #pragma unroll
    for (int c = 0; c < 2; ++c)
      __builtin_amdgcn_global_load_lds(
          (const __attribute__((address_space(1))) unsigned int*)(aptr[c] + k32),
          (__attribute__((address_space(3))) unsigned int*)(&As[abuf][(tid + c * 512) * 8]),
          16, 0, 0);
  };

  float rB[8];
  auto LOAD_B = [&](int t) {
    if (doB) {
      const float* p = bbase + (long)t * 32 * HID;
      #pragma unroll
      for (int j = 0; j < 8; ++j) rB[j] = p[(long)j * HID];
    }
  };

  f32x4 acc[4][2];
  #pragma unroll
  for (int i = 0; i < 4; ++i)
    #pragma unroll
    for (int j = 0; j < 2; ++j) acc[i][j] = (f32x4)0.0f;

  LOAD_B(0);
  STAGE_A(0, 0);

  const int NIT = INTER / 32;   // 128
  for (int t = 0; t < NIT; ++t) {
    const int p = t & 1;
    if (doB) {
      bf16x8 pk;
      #pragma unroll
      for (int j = 0; j < 8; ++j) pk[j] = (__bf16)rB[j];
      *(bf16x8*)&Bbf[p][(bk8 * 64 + bn) * 8] = pk;
    }
    if (t + 1 < NIT) LOAD_B(t + 1);
    // T4 counted wait; wave-uniform divergence (doB aligns to waves 0..3)
    if (t + 1 < NIT && doB) { asm volatile("s_waitcnt vmcnt(8) lgkmcnt(0)" ::: "memory"); }
    else                    { asm volatile("s_waitcnt vmcnt(0) lgkmcnt(0)" ::: "memory"); }
    __builtin_amdgcn_s_barrier();
    asm volatile("" ::: "memory");
    if (t + 1 < NIT) STAGE_A((t + 1) & 1, (long)(t + 1) * 32);
    const int k8 = lane >> 4;
    bf16x8 af[4], bf[2];
    #pragma unroll
    for (int f = 0; f < 4; ++f)
      af[f] = __builtin_bit_cast(bf16x8, *(const ushortx8*)&As[p][(wr * 64 + f * 16 + (lane & 15)) * 32 + k8 * 8]);
    #pragma unroll
    for (int j = 0; j < 2; ++j)
      bf[j] = __builtin_bit_cast(bf16x8, *(const ushortx8*)&Bbf[p][(k8 * 64 + wc * 32 + j * 16 + (lane & 15)) * 8]);
    #pragma unroll
    for (int i = 0; i < 4; ++i)
      #pragma unroll
      for (int j = 0; j < 2; ++j)
        acc[i][j] = __builtin_amdgcn_mfma_f32_16x16x32_bf16(af[i], bf[j], acc[i][j], 0, 0, 0);
  }

  const int rtop = off + cnt;
  const int grb  = off + mt * 256 + wr * 64;
  const int gcb  = nt * 64 + wc * 32;
  #pragma unroll
  for (int i = 0; i < 4; ++i) {
    #pragma unroll
    for (int j = 0; j < 2; ++j) {
      int gc = gcb + j * 16 + (lane & 15);
      #pragma unroll
      for (int q = 0; q < 4; ++q) {
        int gr = grb + i * 16 + (lane >> 4) * 4 + q;
        if (gr < rtop) {
          int a = rows[gr];
          y[(long)a * HID + gc] = acc[i][j][q];
        }
      }
    }
  }
}

// ---------------- combine: out[t] = ew0*Y[2t] + ew1*Y[2t+1] ----------------
__global__ void combine_kernel(const float* __restrict__ Y,
                               const float* __restrict__ ew,
                               float* __restrict__ out)
{
  int idx = blockIdx.x * 256 + threadIdx.x;
  int t = idx >> 9;
  int h = (idx & 511) * 4;
  float w0 = ew[2 * t], w1 = ew[2 * t + 1];
  float4 y0 = *(const float4*)&Y[(long)(2 * t) * HID + h];
  float4 y1 = *(const float4*)&Y[(long)(2 * t + 1) * HID + h];
  float4 o;
  o.x = w0 * y0.x + w1 * y1.x;
  o.y = w0 * y0.y + w1 * y1.y;
  o.z = w0 * y0.z + w1 * y1.z;
  o.w = w0 * y0.w + w1 * y1.w;
  *(float4*)&out[(long)t * HID + h] = o;
}

extern "C" void kernel_launch(void* const* d_in, const int* in_sizes, int n_in,
                              void* d_out, int out_size, void* d_ws, size_t ws_size,
                              hipStream_t stream) {
  const float* x   = (const float*)d_in[0];
  const int*   eix = (const int*)d_in[1];
  const float* ew  = (const float*)d_in[2];
  const float* w1  = (const float*)d_in[3];
  const float* w2  = (const float*)d_in[4];
  const float* w3  = (const float*)d_in[5];
  float* out = (float*)d_out;

  char* ws = (char*)d_ws;
  unsigned short* xb  = (unsigned short*)(ws + XB_OFF);
  unsigned short* gb  = (unsigned short*)(ws + GB_OFF);
  float*          y   = (float*)(ws + Y_OFF);
  int*            rows  = (int*)(ws + ROWS_OFF);
  int*            offs  = (int*)(ws + OFFS_OFF);
  int*            tiles = (int*)(ws + TILE_OFF);

  prep_kernel<<<4097, 256, 0, stream>>>(eix, x, xb, rows, offs, tiles);
  gemm_gateup<<<dim3(INTER / 64, NTSLOTS), 512, 0, stream>>>(
      xb, w1, w3, gb, rows, offs, tiles);
  gemm_down<<<dim3(HID / 64, NTSLOTS), 512, 0, stream>>>(
      gb, w2, y, rows, offs, tiles);
  combine_kernel<<<4096, 256, 0, stream>>>(y, ew, out);
}